// Round 1
// baseline (484.693 us; speedup 1.0000x reference)
//
#include <hip/hip_runtime.h>
#include <math.h>

// Problem constants (fixed-shape problem)
#define B 256
#define W 512
#define F 512
#define N 512

// -----------------------------------------------------------------------------
// Kernel 1: per-sample prep.  One block per b, 512 threads.
//   phase 0: t[f]  = sum_w x[b,w,f] * w[w]          (streams x[b], 1 MB)
//   phase 1: Q[n]  = sum_f t[f] * Wq[f,n]           (Wq from L2)
//   phase 2: r[f'] = (1/sqrt(N)) * sum_n Q[n]*Wk[f',n]   (Wk rows, L2)
// -----------------------------------------------------------------------------
__global__ __launch_bounds__(512) void prep_kernel(
    const float* __restrict__ x,
    const float* __restrict__ Wk,
    const float* __restrict__ Wq,
    const float* __restrict__ wvec,
    float* __restrict__ r_out)
{
    __shared__ float s_w[W];
    __shared__ float s_t[F];
    __shared__ float s_q[N];

    const int b   = blockIdx.x;
    const int tid = threadIdx.x;

    s_w[tid] = wvec[tid];
    __syncthreads();

    // phase 0: t[tid] = sum_w x[b,w,tid] * w[w]  (coalesced: lanes span f)
    const float* xb = x + (size_t)b * W * F;
    float acc = 0.f;
#pragma unroll 8
    for (int w = 0; w < W; ++w) {
        acc += xb[(size_t)w * F + tid] * s_w[w];
    }
    s_t[tid] = acc;
    __syncthreads();

    // phase 1: Q[tid] = sum_f t[f] * Wq[f,tid]  (coalesced over n=tid)
    float q = 0.f;
#pragma unroll 8
    for (int f = 0; f < F; ++f) {
        q += s_t[f] * Wq[(size_t)f * N + tid];
    }
    s_q[tid] = q;
    __syncthreads();

    // phase 2: r[tid] = inv_sqrtN * sum_n Q[n] * Wk[tid,n]
    // (each lane reads its own Wk row as float4; Wk is 1 MB -> L2 resident)
    const float4* wkrow = (const float4*)(Wk + (size_t)tid * N);
    float rv = 0.f;
#pragma unroll 4
    for (int n4 = 0; n4 < N / 4; ++n4) {
        float4 kv = wkrow[n4];
        float4 qv = *(const float4*)(&s_q[n4 * 4]);  // LDS broadcast b128
        rv += kv.x * qv.x + kv.y * qv.y + kv.z * qv.z + kv.w * qv.w;
    }
    const float inv_sqrtN = 0.04419417382415922f;  // 1/sqrt(512)
    r_out[(size_t)b * F + tid] = rv * inv_sqrtN;
}

// -----------------------------------------------------------------------------
// Kernel 2: fused scores -> online softmax -> c accumulation -> out = c @ Wv.
// One block per b, 8 waves.  Wave wv handles words [wv*64, wv*64+64).
// Lane holds 8 x-values per row (two float4 at f = lane*4 and 256+lane*4);
// the c accumulator lives in the same per-lane layout.
// -----------------------------------------------------------------------------
__global__ __launch_bounds__(512) void attn_kernel(
    const float* __restrict__ x,
    const float* __restrict__ Wv,
    const float* __restrict__ r_in,
    float* __restrict__ out)
{
    const int b    = blockIdx.x;
    const int tid  = threadIdx.x;
    const int lane = tid & 63;
    const int wv   = tid >> 6;   // wave id 0..7

    __shared__ float s_c[8][F];      // per-wave weighted-x partials (16 KB)
    __shared__ float s_m[8];
    __shared__ float s_l[8];
    __shared__ float s_cf[F];        // combined c / L

    const float* xb = x + (size_t)b * W * F;
    const float* rb = r_in + (size_t)b * F;

    // r fragment in the same layout as the x loads
    const float4 r0 = *(const float4*)(rb + lane * 4);
    const float4 r1 = *(const float4*)(rb + 256 + lane * 4);

    float m = -INFINITY;
    float l = 0.f;
    float4 c0 = make_float4(0.f, 0.f, 0.f, 0.f);
    float4 c1 = make_float4(0.f, 0.f, 0.f, 0.f);

#pragma unroll 2
    for (int i = 0; i < 64; ++i) {
        const int w = wv * 64 + i;
        const float* row = xb + (size_t)w * F;
        const float4 x0 = *(const float4*)(row + lane * 4);
        const float4 x1 = *(const float4*)(row + 256 + lane * 4);

        // score = x_row . r  (scale already folded into r)
        float d = x0.x * r0.x + x0.y * r0.y + x0.z * r0.z + x0.w * r0.w
                + x1.x * r1.x + x1.y * r1.y + x1.z * r1.z + x1.w * r1.w;
#pragma unroll
        for (int off = 32; off >= 1; off >>= 1) d += __shfl_xor(d, off, 64);

        // online softmax update (wave-uniform values)
        const float mnew  = fmaxf(m, d);
        const float scale = __expf(m - mnew);   // exp(-inf)=0 on first iter
        const float p     = __expf(d - mnew);
        l = l * scale + p;
        c0.x = c0.x * scale + p * x0.x;
        c0.y = c0.y * scale + p * x0.y;
        c0.z = c0.z * scale + p * x0.z;
        c0.w = c0.w * scale + p * x0.w;
        c1.x = c1.x * scale + p * x1.x;
        c1.y = c1.y * scale + p * x1.y;
        c1.z = c1.z * scale + p * x1.z;
        c1.w = c1.w * scale + p * x1.w;
        m = mnew;
    }

    // stash per-wave state
    *(float4*)&s_c[wv][lane * 4]       = c0;
    *(float4*)&s_c[wv][256 + lane * 4] = c1;
    if (lane == 0) { s_m[wv] = m; s_l[wv] = l; }
    __syncthreads();

    // combine 8 waves (every thread computes the uniform M, L)
    float M = -INFINITY;
#pragma unroll
    for (int j = 0; j < 8; ++j) M = fmaxf(M, s_m[j]);
    float L = 0.f;
    float alpha[8];
#pragma unroll
    for (int j = 0; j < 8; ++j) {
        alpha[j] = __expf(s_m[j] - M);
        L += alpha[j] * s_l[j];
    }
    const float invL = 1.f / L;

    float cf = 0.f;
#pragma unroll
    for (int j = 0; j < 8; ++j) cf += alpha[j] * s_c[j][tid];
    s_cf[tid] = cf * invL;
    __syncthreads();

    // out[b,n] = sum_f c[f] * Wv[f,n]   (coalesced over n=tid, Wv from L2)
    float o = 0.f;
#pragma unroll 8
    for (int f = 0; f < F; ++f) {
        o += s_cf[f] * Wv[(size_t)f * N + tid];
    }
    out[(size_t)b * N + tid] = o;
}

// -----------------------------------------------------------------------------
// Launcher
// inputs: x (B,W,F), weight_k (F,N), weight_q (F,N), weight_v (F,N), w (W,1)
// output: (B, N) float32
// workspace: r buffer, B*F floats = 512 KB
// -----------------------------------------------------------------------------
extern "C" void kernel_launch(void* const* d_in, const int* in_sizes, int n_in,
                              void* d_out, int out_size, void* d_ws, size_t ws_size,
                              hipStream_t stream)
{
    const float* x    = (const float*)d_in[0];
    const float* Wk   = (const float*)d_in[1];
    const float* Wq   = (const float*)d_in[2];
    const float* Wv   = (const float*)d_in[3];
    const float* wvec = (const float*)d_in[4];
    float* out = (float*)d_out;
    float* r   = (float*)d_ws;   // B*F floats

    prep_kernel<<<B, 512, 0, stream>>>(x, Wk, Wq, wvec, r);
    attn_kernel<<<B, 512, 0, stream>>>(x, Wv, r, out);
}

// Round 2
// 465.451 us; speedup vs baseline: 1.0413x; 1.0413x over previous
//
#include <hip/hip_runtime.h>
#include <math.h>

// Problem constants (fixed shape)
#define B 256
#define W 512
#define F 512
#define N 512
#define GPART 4            // partial blocks per sample in kernel A
#define WPG (W / GPART)    // 128 words per A-block

// -----------------------------------------------------------------------------
// Kernel A: t partials.  grid = B*GPART, 512 threads (4 blocks/CU -> 32 waves/CU).
// Block (b,g) handles words [g*128, g*128+128).  Thread = (ws, f4):
//   ws = tid>>7 handles 32 words, f4 = tid&127 handles f = f4*4..f4*4+3 (float4).
// Writes t_part[b][g][f] = sum over this block's words of x[b,w,f]*wvec[w].
// -----------------------------------------------------------------------------
__global__ __launch_bounds__(512) void tpart_kernel(
    const float* __restrict__ x,
    const float* __restrict__ wvec,
    float* __restrict__ t_part)
{
    const int blk = blockIdx.x;
    const int g   = blk & (GPART - 1);
    const int b   = blk >> 2;
    const int tid = threadIdx.x;
    const int ws  = tid >> 7;     // 0..3
    const int f4  = tid & 127;

    __shared__ float s_w[WPG];
    __shared__ float s_part[4][F];

    if (tid < WPG) s_w[tid] = wvec[g * WPG + tid];
    __syncthreads();

    const float* xb = x + (size_t)b * W * F + (size_t)(g * WPG + ws * 32) * F;
    float4 acc = make_float4(0.f, 0.f, 0.f, 0.f);
#pragma unroll 8
    for (int i = 0; i < 32; ++i) {
        const float4 xv = *(const float4*)(xb + (size_t)i * F + f4 * 4);
        const float  ww = s_w[ws * 32 + i];
        acc.x += xv.x * ww; acc.y += xv.y * ww;
        acc.z += xv.z * ww; acc.w += xv.w * ww;
    }
    *(float4*)&s_part[ws][f4 * 4] = acc;
    __syncthreads();

    const float t = (s_part[0][tid] + s_part[1][tid])
                  + (s_part[2][tid] + s_part[3][tid]);
    t_part[(size_t)blk * F + tid] = t;
}

// -----------------------------------------------------------------------------
// Kernel B: reduce t partials, Q = t@Wq, r = (1/sqrt(N)) * Wk@Q.
// grid = B, 512 threads.  Weights are L2-resident (1 MB each).
// -----------------------------------------------------------------------------
__global__ __launch_bounds__(512) void qr_kernel(
    const float* __restrict__ t_part,
    const float* __restrict__ Wq,
    const float* __restrict__ Wk,
    float* __restrict__ r_out)
{
    __shared__ float s_t[F];
    __shared__ float s_q[N];
    const int b = blockIdx.x, tid = threadIdx.x;

    float t = 0.f;
#pragma unroll
    for (int g = 0; g < GPART; ++g)
        t += t_part[((size_t)b * GPART + g) * F + tid];
    s_t[tid] = t;
    __syncthreads();

    // Q[tid] = sum_f t[f] * Wq[f,tid]; 4 independent accumulators
    float q0 = 0.f, q1 = 0.f, q2 = 0.f, q3 = 0.f;
#pragma unroll 4
    for (int f = 0; f < F; f += 4) {
        q0 += s_t[f + 0] * Wq[(size_t)(f + 0) * N + tid];
        q1 += s_t[f + 1] * Wq[(size_t)(f + 1) * N + tid];
        q2 += s_t[f + 2] * Wq[(size_t)(f + 2) * N + tid];
        q3 += s_t[f + 3] * Wq[(size_t)(f + 3) * N + tid];
    }
    s_q[tid] = (q0 + q1) + (q2 + q3);
    __syncthreads();

    // r[tid] = scale * sum_n Q[n] * Wk[tid,n]  (per-lane float4 row reads, L2)
    const float4* wkrow = (const float4*)(Wk + (size_t)tid * N);
    float r0 = 0.f, r1 = 0.f, r2 = 0.f, r3 = 0.f;
#pragma unroll 8
    for (int n4 = 0; n4 < N / 4; ++n4) {
        const float4 kv = wkrow[n4];
        const float4 qv = *(const float4*)&s_q[n4 * 4];
        r0 += kv.x * qv.x; r1 += kv.y * qv.y;
        r2 += kv.z * qv.z; r3 += kv.w * qv.w;
    }
    r_out[(size_t)b * F + tid] =
        ((r0 + r1) + (r2 + r3)) * 0.04419417382415922f;  // 1/sqrt(512)
}

// -----------------------------------------------------------------------------
// Kernel C: online softmax + c accumulation + out = c@Wv.
// grid = B, 512 threads (8 waves).  Wave wv handles words [wv*64, wv*64+64),
// TWO words per iteration with interleaved butterfly reductions for ILP.
// -----------------------------------------------------------------------------
__global__ __launch_bounds__(512) void attn_kernel(
    const float* __restrict__ x,
    const float* __restrict__ Wv,
    const float* __restrict__ r_in,
    float* __restrict__ out)
{
    const int b    = blockIdx.x;
    const int tid  = threadIdx.x;
    const int lane = tid & 63;
    const int wv   = tid >> 6;

    __shared__ float s_c[8][F];
    __shared__ float s_m[8];
    __shared__ float s_l[8];
    __shared__ float s_cf[F];

    const float* xb = x + (size_t)b * W * F;
    const float* rb = r_in + (size_t)b * F;
    const float4 r0 = *(const float4*)(rb + lane * 4);
    const float4 r1 = *(const float4*)(rb + 256 + lane * 4);

    float m = -INFINITY, l = 0.f;
    float4 c0 = make_float4(0.f, 0.f, 0.f, 0.f);
    float4 c1 = make_float4(0.f, 0.f, 0.f, 0.f);

#pragma unroll 2
    for (int i = 0; i < 64; i += 2) {
        const float* rowA = xb + (size_t)(wv * 64 + i) * F;
        const float* rowB = rowA + F;
        const float4 a0 = *(const float4*)(rowA + lane * 4);
        const float4 a1 = *(const float4*)(rowA + 256 + lane * 4);
        const float4 b0 = *(const float4*)(rowB + lane * 4);
        const float4 b1 = *(const float4*)(rowB + 256 + lane * 4);

        float dA = a0.x * r0.x + a0.y * r0.y + a0.z * r0.z + a0.w * r0.w
                 + a1.x * r1.x + a1.y * r1.y + a1.z * r1.z + a1.w * r1.w;
        float dB = b0.x * r0.x + b0.y * r0.y + b0.z * r0.z + b0.w * r0.w
                 + b1.x * r1.x + b1.y * r1.y + b1.z * r1.z + b1.w * r1.w;
#pragma unroll
        for (int off = 32; off >= 1; off >>= 1) {
            dA += __shfl_xor(dA, off, 64);
            dB += __shfl_xor(dB, off, 64);
        }

        // online update, word A
        float mn = fmaxf(m, dA);
        float sc = __expf(m - mn);
        float p  = __expf(dA - mn);
        l = l * sc + p;
        c0.x = c0.x * sc + p * a0.x; c0.y = c0.y * sc + p * a0.y;
        c0.z = c0.z * sc + p * a0.z; c0.w = c0.w * sc + p * a0.w;
        c1.x = c1.x * sc + p * a1.x; c1.y = c1.y * sc + p * a1.y;
        c1.z = c1.z * sc + p * a1.z; c1.w = c1.w * sc + p * a1.w;
        m = mn;

        // online update, word B
        mn = fmaxf(m, dB);
        sc = __expf(m - mn);
        p  = __expf(dB - mn);
        l = l * sc + p;
        c0.x = c0.x * sc + p * b0.x; c0.y = c0.y * sc + p * b0.y;
        c0.z = c0.z * sc + p * b0.z; c0.w = c0.w * sc + p * b0.w;
        c1.x = c1.x * sc + p * b1.x; c1.y = c1.y * sc + p * b1.y;
        c1.z = c1.z * sc + p * b1.z; c1.w = c1.w * sc + p * b1.w;
        m = mn;
    }

    *(float4*)&s_c[wv][lane * 4]       = c0;
    *(float4*)&s_c[wv][256 + lane * 4] = c1;
    if (lane == 0) { s_m[wv] = m; s_l[wv] = l; }
    __syncthreads();

    float M = -INFINITY;
#pragma unroll
    for (int j = 0; j < 8; ++j) M = fmaxf(M, s_m[j]);
    float L = 0.f;
    float alpha[8];
#pragma unroll
    for (int j = 0; j < 8; ++j) {
        alpha[j] = __expf(s_m[j] - M);
        L += alpha[j] * s_l[j];
    }
    const float invL = 1.f / L;

    float cf = 0.f;
#pragma unroll
    for (int j = 0; j < 8; ++j) cf += alpha[j] * s_c[j][tid];
    s_cf[tid] = cf * invL;
    __syncthreads();

    // out[b,tid] = sum_f c[f] * Wv[f,tid]; 4 independent accumulators
    float o0 = 0.f, o1 = 0.f, o2 = 0.f, o3 = 0.f;
#pragma unroll 4
    for (int f = 0; f < F; f += 4) {
        o0 += s_cf[f + 0] * Wv[(size_t)(f + 0) * N + tid];
        o1 += s_cf[f + 1] * Wv[(size_t)(f + 1) * N + tid];
        o2 += s_cf[f + 2] * Wv[(size_t)(f + 2) * N + tid];
        o3 += s_cf[f + 3] * Wv[(size_t)(f + 3) * N + tid];
    }
    out[(size_t)b * N + tid] = (o0 + o1) + (o2 + o3);
}

// -----------------------------------------------------------------------------
// Launcher.  ws layout: t_part = B*GPART*F floats (2 MB), then r = B*F (512 KB).
// -----------------------------------------------------------------------------
extern "C" void kernel_launch(void* const* d_in, const int* in_sizes, int n_in,
                              void* d_out, int out_size, void* d_ws, size_t ws_size,
                              hipStream_t stream)
{
    const float* x    = (const float*)d_in[0];
    const float* Wk   = (const float*)d_in[1];
    const float* Wq   = (const float*)d_in[2];
    const float* Wv   = (const float*)d_in[3];
    const float* wvec = (const float*)d_in[4];
    float* out    = (float*)d_out;
    float* t_part = (float*)d_ws;
    float* r      = t_part + (size_t)B * GPART * F;

    tpart_kernel<<<B * GPART, 512, 0, stream>>>(x, wvec, t_part);
    qr_kernel<<<B, 512, 0, stream>>>(t_part, Wq, Wk, r);
    attn_kernel<<<B, 512, 0, stream>>>(x, Wv, r, out);
}